// Round 9
// baseline (1074.415 us; speedup 1.0000x reference)
//
#include <hip/hip_runtime.h>
#include <hip/hip_bf16.h>
#include <math.h>

#define N_NODES 100000
#define N_EDGES 1600000
#define F_IN 64
#define H_DIM 200
#define N_GRAPHS 512
#define NB_SCAN 98   // ceil(100000 / 1024)

#define WTK 256              // W table k-stride: 224 main + 32-entry overlap-tail block
#define WT_PER (224 * WTK)   // one padded weight table (shorts)
#define SA 208               // LDS A-tile stride (shorts); 416B rows, 16B-aligned

typedef __attribute__((ext_vector_type(8))) short short8v;   // 8 bf16 = 4 VGPR
typedef __attribute__((ext_vector_type(4))) float f32x4;     // mfma accumulator

// ---------------- CSR build: histogram by dst ----------------
__global__ void hist_kernel(const int* __restrict__ ei, int* __restrict__ cnt) {
    int i = blockIdx.x * blockDim.x + threadIdx.x;
    if (i < N_EDGES) atomicAdd(&cnt[ei[N_EDGES + i]], 1);
}

__global__ __launch_bounds__(256) void scan_part(const int* __restrict__ deg,
                                                 int* __restrict__ bsums) {
    int b = blockIdx.x, t = threadIdx.x;
    int i0 = b * 1024 + t * 4;
    int s = 0;
    #pragma unroll
    for (int k = 0; k < 4; ++k) { int i = i0 + k; if (i < N_NODES) s += deg[i]; }
    #pragma unroll
    for (int off = 32; off > 0; off >>= 1) s += __shfl_down(s, off, 64);
    __shared__ int wsum[4];
    if ((t & 63) == 0) wsum[t >> 6] = s;
    __syncthreads();
    if (t == 0) bsums[b] = wsum[0] + wsum[1] + wsum[2] + wsum[3];
}

__global__ void scan_tops(int* __restrict__ bsums, int* __restrict__ ptr) {
    __shared__ int sh[128];
    int t = threadIdx.x;
    int v = (t < NB_SCAN) ? bsums[t] : 0;
    sh[t] = v;
    __syncthreads();
    for (int off = 1; off < 128; off <<= 1) {
        int a = sh[t];
        int add = (t >= off) ? sh[t - off] : 0;
        __syncthreads();
        sh[t] = a + add;
        __syncthreads();
    }
    if (t < NB_SCAN) bsums[t] = sh[t] - v;
    if (t == 127) ptr[N_NODES] = sh[127];
}

__global__ __launch_bounds__(256) void scan_fin(int* __restrict__ deg_cursor,
                                                const int* __restrict__ bsums,
                                                int* __restrict__ ptr) {
    int b = blockIdx.x, t = threadIdx.x;
    int i0 = b * 1024 + t * 4;
    int d[4]; int s = 0;
    #pragma unroll
    for (int k = 0; k < 4; ++k) {
        int i = i0 + k;
        d[k] = (i < N_NODES) ? deg_cursor[i] : 0;
        s += d[k];
    }
    __shared__ int sh[256];
    sh[t] = s;
    __syncthreads();
    for (int off = 1; off < 256; off <<= 1) {
        int a = sh[t];
        int add = (t >= off) ? sh[t - off] : 0;
        __syncthreads();
        sh[t] = a + add;
        __syncthreads();
    }
    int run = bsums[b] + sh[t] - s;
    #pragma unroll
    for (int k = 0; k < 4; ++k) {
        int i = i0 + k;
        if (i < N_NODES) { ptr[i] = run; deg_cursor[i] = run; run += d[k]; }
    }
}

__global__ void fill_kernel(const int* __restrict__ ei, int* __restrict__ cursor,
                            int* __restrict__ csr_src) {
    int i = blockIdx.x * blockDim.x + threadIdx.x;
    if (i < N_EDGES) {
        int s = ei[i];
        int d = ei[N_EDGES + i];
        int p = atomicAdd(&cursor[d], 1);
        csr_src[p] = s;
    }
}

// helpers
__device__ __forceinline__ short f2bf(float f) {
    __hip_bfloat16 h = __float2bfloat16(f);
    return *reinterpret_cast<const short*>(&h);
}
__device__ __forceinline__ float bf2f(short s) {
    return __uint_as_float(((unsigned)(unsigned short)s) << 16);
}
__device__ __forceinline__ float4 bf4_to_f4(uint2 u) {
    float4 r;
    r.x = __uint_as_float(u.x << 16);
    r.y = __uint_as_float(u.x & 0xffff0000u);
    r.z = __uint_as_float(u.y << 16);
    r.w = __uint_as_float(u.y & 0xffff0000u);
    return r;
}

// ---------------- X fp32 -> bf16 (halves layer-1 gather bytes) ----------------
__global__ void prep_x(const float* __restrict__ X, short* __restrict__ Xb) {
    int i = blockIdx.x * 256 + threadIdx.x;
    if (i < N_NODES * 64) Xb[i] = f2bf(X[i]);
}

// ---------------- weight prep: W[K][200] fp32 -> hi/lo bf16 tables [224 cols][WTK k] ----
// k' in [0,224): normal (zero-padded). k' in [224,256): overlap-tail block for the
// tail MFMA slice that reads A k in [176,208): first 16 entries (k 176..191,
// already counted in full slice 5) are ZERO; last 16 map to k 192..207.
__global__ void prep_w(const float* __restrict__ W1a, const float* __restrict__ W1b,
                       const float* __restrict__ W2a, const float* __restrict__ W2b,
                       short* __restrict__ wt) {
    int idx = blockIdx.x * 256 + threadIdx.x;
    if (idx >= 4 * WT_PER) return;
    int tsel = idx / WT_PER, rem = idx % WT_PER;
    int c = rem / WTK, kp = rem % WTK;
    const float* W = (tsel == 0) ? W1a : (tsel == 1) ? W1b : (tsel == 2) ? W2a : W2b;
    int K = (tsel == 0) ? 64 : 200;
    int k; bool valid;
    if (kp < 224) { k = kp; valid = (k < K) && (k < 200); }
    else { int m = kp - 224; k = 192 + (m - 16); valid = (m >= 16) && (k < K) && (k < 200); }
    float v = (valid && c < 200) ? W[k * 200 + c] : 0.0f;
    short hi = f2bf(v);
    short lo = f2bf(v - bf2f(hi));
    wt[(2 * tsel) * WT_PER + rem] = hi;
    wt[(2 * tsel + 1) * WT_PER + rem] = lo;
}

// ---- split-bf16 MFMA tile GEMM (acc += Ah*Bh + Ah*Bl + Al*Bh) ----
// A: row=l&15, k=8*(l>>4)+j ; B: col=l&15, same k ; acc: col=l&15, row=(l>>4)*4+i
// NKS full 32-k slices; TAIL adds the overlap slice (A k=176+8*lhi, B tail block).
template <int NKS, bool TAIL>
__device__ __forceinline__ void gemm_split(const short* __restrict__ SLh,
                                           const short* __restrict__ SLl,
                                           const short* __restrict__ Wh,
                                           const short* __restrict__ Wl,
                                           int l15, int lhi, int rt, int ch,
                                           f32x4 acc[7]) {
    const int arow = (rt * 16 + l15) * SA;
    for (int ks = 0; ks < NKS; ++ks) {
        const int k0 = ks * 32 + 8 * lhi;
        short8v ah = *reinterpret_cast<const short8v*>(SLh + arow + k0);
        short8v al = *reinterpret_cast<const short8v*>(SLl + arow + k0);
        #pragma unroll
        for (int ct = 0; ct < 7; ++ct) {
            const int tile = ch * 7 + ct;
            if (tile < 13) {   // tile 13 would be all-zero cols; ch is wave-uniform
                const int wof = (tile * 16 + l15) * WTK + k0;
                short8v bh = *reinterpret_cast<const short8v*>(Wh + wof);
                short8v bl = *reinterpret_cast<const short8v*>(Wl + wof);
                acc[ct] = __builtin_amdgcn_mfma_f32_16x16x32_bf16(ah, bh, acc[ct], 0, 0, 0);
                acc[ct] = __builtin_amdgcn_mfma_f32_16x16x32_bf16(ah, bl, acc[ct], 0, 0, 0);
                acc[ct] = __builtin_amdgcn_mfma_f32_16x16x32_bf16(al, bh, acc[ct], 0, 0, 0);
            }
        }
    }
    if (TAIL) {
        const int k0a = 176 + 8 * lhi;           // A k in [176,208) — fits SA=208
        short8v ah = *reinterpret_cast<const short8v*>(SLh + arow + k0a);
        short8v al = *reinterpret_cast<const short8v*>(SLl + arow + k0a);
        const int k0b = 224 + 8 * lhi;           // B tail block
        #pragma unroll
        for (int ct = 0; ct < 7; ++ct) {
            const int tile = ch * 7 + ct;
            if (tile < 13) {
                const int wof = (tile * 16 + l15) * WTK + k0b;
                short8v bh = *reinterpret_cast<const short8v*>(Wh + wof);
                short8v bl = *reinterpret_cast<const short8v*>(Wl + wof);
                acc[ct] = __builtin_amdgcn_mfma_f32_16x16x32_bf16(ah, bh, acc[ct], 0, 0, 0);
                acc[ct] = __builtin_amdgcn_mfma_f32_16x16x32_bf16(ah, bl, acc[ct], 0, 0, 0);
                acc[ct] = __builtin_amdgcn_mfma_f32_16x16x32_bf16(al, bh, acc[ct], 0, 0, 0);
            }
        }
    }
}

// ---------------- fused GIN layer: gather -> split-MFMA GEMM1 -> relu -> GEMM2 -> BN ----
// 512 threads = 8 waves; 64 nodes/block; LDS 52KB -> 3 blocks/CU = 24 waves/CU (75%)
// with an ~85-reg budget (launch_bounds(512,6)) — spill-free, unlike the (1024,8) cap.
// Gather: each wave owns 8 rows; 8-deep load batches into 2 accumulators.
// GEMM: wave = (row-tile rt = wid>>1) x (col-half ch = wid&1, 7 tiles, tile13 skipped).
template <bool FIRST>
__global__ __launch_bounds__(512, 6) void gin_mfma(
        const void* __restrict__ Xv,                 // bf16 [N][64] or bf16 [N][200]
        const int* __restrict__ ptr, const int* __restrict__ srcl,
        const float* __restrict__ eps_p,
        const short* __restrict__ Wa2,               // hi table; lo at +WT_PER
        const float* __restrict__ ba,
        const short* __restrict__ Wb2, const float* __restrict__ bb,
        const float* __restrict__ gamma, const float* __restrict__ beta,
        const float* __restrict__ mean, const float* __restrict__ var,
        void* __restrict__ outv) {                   // bf16 [N][200] or fp32 [N][200]
    __shared__ __align__(16) short SLh[64 * SA];     // 26,624 B
    __shared__ __align__(16) short SLl[64 * SA];     // 26,624 B
    const int t = threadIdx.x;
    const int lane = t & 63;
    const int wid = t >> 6;
    const int node0 = blockIdx.x * 64;
    const float ep = 1.0f + eps_p[0];

    // ---- zero the k-pad cols [200,208) so garbage never reaches MFMA ----
    {
        int row = t >> 3, c = 200 + (t & 7);         // 512 threads = 64 rows x 8 cols
        SLh[row * SA + c] = 0;
        SLl[row * SA + c] = 0;
    }

    // ---- gather phase: 8 rows per wave, 8-deep ILP, 2 accumulators ----
    if (FIRST) {
        const short* Xb = (const short*)Xv;          // bf16 [N][64]
        for (int rr = 0; rr < 8; ++rr) {
            int row = wid * 8 + rr;
            int node = node0 + row;
            if (node >= N_NODES) break;
            int b = ptr[node], e = ptr[node + 1];
            float a0 = ep * bf2f(Xb[(size_t)node * 64 + lane]);
            float a1 = 0.f;
            int j = b;
            for (; j + 8 <= e; j += 8) {
                int s0 = srcl[j+0], s1 = srcl[j+1], s2 = srcl[j+2], s3 = srcl[j+3];
                int s4 = srcl[j+4], s5 = srcl[j+5], s6 = srcl[j+6], s7 = srcl[j+7];
                short f0 = Xb[(size_t)s0 * 64 + lane];
                short f1 = Xb[(size_t)s1 * 64 + lane];
                short f2 = Xb[(size_t)s2 * 64 + lane];
                short f3 = Xb[(size_t)s3 * 64 + lane];
                short f4 = Xb[(size_t)s4 * 64 + lane];
                short f5 = Xb[(size_t)s5 * 64 + lane];
                short f6 = Xb[(size_t)s6 * 64 + lane];
                short f7 = Xb[(size_t)s7 * 64 + lane];
                a0 += (bf2f(f0) + bf2f(f2)) + (bf2f(f4) + bf2f(f6));
                a1 += (bf2f(f1) + bf2f(f3)) + (bf2f(f5) + bf2f(f7));
            }
            if (j + 4 <= e) {
                int s0 = srcl[j+0], s1 = srcl[j+1], s2 = srcl[j+2], s3 = srcl[j+3];
                a0 += bf2f(Xb[(size_t)s0 * 64 + lane]) + bf2f(Xb[(size_t)s2 * 64 + lane]);
                a1 += bf2f(Xb[(size_t)s1 * 64 + lane]) + bf2f(Xb[(size_t)s3 * 64 + lane]);
                j += 4;
            }
            for (; j < e; ++j) a0 += bf2f(Xb[(size_t)srcl[j] * 64 + lane]);
            float s = a0 + a1;
            short hi = f2bf(s);
            SLh[row * SA + lane] = hi;               // k = lane < 64
            SLl[row * SA + lane] = f2bf(s - bf2f(hi));
        }
    } else {
        const uint2* H2 = (const uint2*)Xv;          // bf16 rows: 50 x uint2
        for (int rr = 0; rr < 8; ++rr) {
            int row = wid * 8 + rr;
            int node = node0 + row;
            if (node >= N_NODES) break;
            int b = ptr[node], e = ptr[node + 1];
            if (lane < 50) {
                float4 fs = bf4_to_f4(H2[(size_t)node * 50 + lane]);
                float4 A0 = make_float4(ep * fs.x, ep * fs.y, ep * fs.z, ep * fs.w);
                float4 A1 = make_float4(0.f, 0.f, 0.f, 0.f);
                int j = b;
                for (; j + 8 <= e; j += 8) {
                    int s0 = srcl[j+0], s1 = srcl[j+1], s2 = srcl[j+2], s3 = srcl[j+3];
                    int s4 = srcl[j+4], s5 = srcl[j+5], s6 = srcl[j+6], s7 = srcl[j+7];
                    uint2 u0 = H2[(size_t)s0 * 50 + lane];
                    uint2 u1 = H2[(size_t)s1 * 50 + lane];
                    uint2 u2 = H2[(size_t)s2 * 50 + lane];
                    uint2 u3 = H2[(size_t)s3 * 50 + lane];
                    uint2 u4 = H2[(size_t)s4 * 50 + lane];
                    uint2 u5 = H2[(size_t)s5 * 50 + lane];
                    uint2 u6 = H2[(size_t)s6 * 50 + lane];
                    uint2 u7 = H2[(size_t)s7 * 50 + lane];
                    float4 f0 = bf4_to_f4(u0), f1 = bf4_to_f4(u1);
                    float4 f2 = bf4_to_f4(u2), f3 = bf4_to_f4(u3);
                    float4 f4 = bf4_to_f4(u4), f5 = bf4_to_f4(u5);
                    float4 f6 = bf4_to_f4(u6), f7 = bf4_to_f4(u7);
                    A0.x += (f0.x + f2.x) + (f4.x + f6.x);
                    A0.y += (f0.y + f2.y) + (f4.y + f6.y);
                    A0.z += (f0.z + f2.z) + (f4.z + f6.z);
                    A0.w += (f0.w + f2.w) + (f4.w + f6.w);
                    A1.x += (f1.x + f3.x) + (f5.x + f7.x);
                    A1.y += (f1.y + f3.y) + (f5.y + f7.y);
                    A1.z += (f1.z + f3.z) + (f5.z + f7.z);
                    A1.w += (f1.w + f3.w) + (f5.w + f7.w);
                }
                if (j + 4 <= e) {
                    int s0 = srcl[j+0], s1 = srcl[j+1], s2 = srcl[j+2], s3 = srcl[j+3];
                    float4 f0 = bf4_to_f4(H2[(size_t)s0 * 50 + lane]);
                    float4 f1 = bf4_to_f4(H2[(size_t)s1 * 50 + lane]);
                    float4 f2 = bf4_to_f4(H2[(size_t)s2 * 50 + lane]);
                    float4 f3 = bf4_to_f4(H2[(size_t)s3 * 50 + lane]);
                    A0.x += f0.x + f2.x; A0.y += f0.y + f2.y;
                    A0.z += f0.z + f2.z; A0.w += f0.w + f2.w;
                    A1.x += f1.x + f3.x; A1.y += f1.y + f3.y;
                    A1.z += f1.z + f3.z; A1.w += f1.w + f3.w;
                    j += 4;
                }
                for (; j < e; ++j) {
                    float4 f0 = bf4_to_f4(H2[(size_t)srcl[j] * 50 + lane]);
                    A0.x += f0.x; A0.y += f0.y; A0.z += f0.z; A0.w += f0.w;
                }
                float sx = A0.x + A1.x;
                float sy = A0.y + A1.y;
                float sz = A0.z + A1.z;
                float sw = A0.w + A1.w;
                short4 ph, pl;
                ph.x = f2bf(sx); pl.x = f2bf(sx - bf2f(ph.x));
                ph.y = f2bf(sy); pl.y = f2bf(sy - bf2f(ph.y));
                ph.z = f2bf(sz); pl.z = f2bf(sz - bf2f(ph.z));
                ph.w = f2bf(sw); pl.w = f2bf(sw - bf2f(ph.w));
                *reinterpret_cast<short4*>(&SLh[row * SA + 4 * lane]) = ph;
                *reinterpret_cast<short4*>(&SLl[row * SA + 4 * lane]) = pl;
            }
        }
    }
    __syncthreads();

    const int l15 = lane & 15;
    const int lhi = lane >> 4;
    const int rt = wid >> 1;                         // row-tile 0..3
    const int ch = wid & 1;                          // column half

    // ---- single accumulator, reused by both GEMMs (28 regs) ----
    f32x4 acc[7];

    // ---- GEMM1 ----
    #pragma unroll
    for (int i = 0; i < 7; ++i) acc[i] = (f32x4){0.f, 0.f, 0.f, 0.f};
    if (FIRST) gemm_split<2, false>(SLh, SLl, Wa2, Wa2 + WT_PER, l15, lhi, rt, ch, acc);
    else       gemm_split<6, true >(SLh, SLl, Wa2, Wa2 + WT_PER, l15, lhi, rt, ch, acc);
    __syncthreads();   // all A1 reads done before overwrite

    // ---- t = relu(acc + ba) -> SLh/SLl (cols < 200; pads still zero) ----
    #pragma unroll
    for (int i = 0; i < 7; ++i) {
        int col = (ch * 7 + i) * 16 + l15;
        if (col < 200) {
            float bv = ba[col];
            #pragma unroll
            for (int r = 0; r < 4; ++r) {
                int row = rt * 16 + lhi * 4 + r;
                float v = fmaxf(acc[i][r] + bv, 0.0f);
                short hi = f2bf(v);
                SLh[row * SA + col] = hi;
                SLl[row * SA + col] = f2bf(v - bf2f(hi));
            }
        }
    }
    __syncthreads();

    // ---- GEMM2 (K = 200 both layers), same acc re-zeroed ----
    #pragma unroll
    for (int i = 0; i < 7; ++i) acc[i] = (f32x4){0.f, 0.f, 0.f, 0.f};
    gemm_split<6, true>(SLh, SLl, Wb2, Wb2 + WT_PER, l15, lhi, rt, ch, acc);

    // ---- epilogue: relu + BN -> out ----
    #pragma unroll
    for (int i = 0; i < 7; ++i) {
        int col = (ch * 7 + i) * 16 + l15;
        if (col >= 200) continue;
        float bv = bb[col];
        float g0 = gamma[col], bt = beta[col], mn = mean[col];
        float inv = rsqrtf(var[col] + 1e-5f);
        #pragma unroll
        for (int r = 0; r < 4; ++r) {
            int row = rt * 16 + lhi * 4 + r;
            int node = node0 + row;
            if (node < N_NODES) {
                float v = fmaxf(acc[i][r] + bv, 0.0f);
                v = (v - mn) * inv * g0 + bt;
                if (FIRST) ((__hip_bfloat16*)outv)[(size_t)node * 200 + col] = __float2bfloat16(v);
                else       ((float*)outv)[(size_t)node * 200 + col] = v;
            }
        }
    }
}

// ---------------- fused pooling (sum+max) + FC + log_softmax ----------------
__device__ __forceinline__ int lower_bound_dev(const int* a, int n, int v) {
    int lo = 0, hi = n;
    while (lo < hi) { int mid = (lo + hi) >> 1; if (a[mid] < v) lo = mid + 1; else hi = mid; }
    return lo;
}

__global__ __launch_bounds__(256) void pool_fc_kernel(const float* __restrict__ h,
        const int* __restrict__ batch, const float* __restrict__ Wfc,
        const float* __restrict__ bfc, float* __restrict__ out) {
    int g = blockIdx.x;
    __shared__ int range[2];
    if (threadIdx.x == 0) range[0] = lower_bound_dev(batch, N_NODES, g);
    else if (threadIdx.x == 64) range[1] = lower_bound_dev(batch, N_NODES, g + 1);
    __syncthreads();
    int b = range[0], e = range[1];
    int d = threadIdx.x;
    float s0 = 0.f, s1 = 0.f, s2 = 0.f, s3 = 0.f, m = -3.0e38f;
    int n = b;
    if (d < 200) {
        for (; n + 4 <= e; n += 4) {   // 4 independent row-streams
            float v0 = h[(size_t)(n+0) * 200 + d];
            float v1 = h[(size_t)(n+1) * 200 + d];
            float v2 = h[(size_t)(n+2) * 200 + d];
            float v3 = h[(size_t)(n+3) * 200 + d];
            s0 += v0; s1 += v1; s2 += v2; s3 += v3;
            m = fmaxf(m, fmaxf(fmaxf(v0, v1), fmaxf(v2, v3)));
        }
        for (; n < e; ++n) {
            float v = h[(size_t)n * 200 + d];
            s0 += v;
            m = fmaxf(m, v);
        }
    }
    float s = (s0 + s1) + (s2 + s3);
    float c0 = 0.f, c1 = 0.f;
    if (d < 200) {
        c0 = s * Wfc[d * 2 + 0] + m * Wfc[(200 + d) * 2 + 0];
        c1 = s * Wfc[d * 2 + 1] + m * Wfc[(200 + d) * 2 + 1];
    }
    #pragma unroll
    for (int off = 32; off > 0; off >>= 1) {
        c0 += __shfl_down(c0, off, 64);
        c1 += __shfl_down(c1, off, 64);
    }
    __shared__ float r0[4], r1[4];
    int wid = threadIdx.x >> 6;
    if ((threadIdx.x & 63) == 0) { r0[wid] = c0; r1[wid] = c1; }
    __syncthreads();
    if (threadIdx.x == 0) {
        float l0 = r0[0] + r0[1] + r0[2] + r0[3] + bfc[0];
        float l1 = r1[0] + r1[1] + r1[2] + r1[3] + bfc[1];
        float mx = fmaxf(l0, l1);
        float lse = mx + logf(expf(l0 - mx) + expf(l1 - mx));
        out[g * 2 + 0] = l0 - lse;
        out[g * 2 + 1] = l1 - lse;
    }
}

// ---------------- launch ----------------
extern "C" void kernel_launch(void* const* d_in, const int* in_sizes, int n_in,
                              void* d_out, int out_size, void* d_ws, size_t ws_size,
                              hipStream_t stream) {
    const float* x    = (const float*)d_in[0];
    const int*   ei   = (const int*)d_in[1];
    const int*   batch= (const int*)d_in[2];
    const float* eps1 = (const float*)d_in[3];
    const float* W1a  = (const float*)d_in[4];
    const float* b1a  = (const float*)d_in[5];
    const float* W1b  = (const float*)d_in[6];
    const float* b1b  = (const float*)d_in[7];
    const float* bn1g = (const float*)d_in[8];
    const float* bn1b = (const float*)d_in[9];
    const float* bn1m = (const float*)d_in[10];
    const float* bn1v = (const float*)d_in[11];
    const float* eps2 = (const float*)d_in[12];
    const float* W2a  = (const float*)d_in[13];
    const float* b2a  = (const float*)d_in[14];
    const float* W2b  = (const float*)d_in[15];
    const float* b2b  = (const float*)d_in[16];
    const float* bn2g = (const float*)d_in[17];
    const float* bn2b = (const float*)d_in[18];
    const float* bn2m = (const float*)d_in[19];
    const float* bn2v = (const float*)d_in[20];
    const float* Wfc  = (const float*)d_in[21];
    const float* bfc  = (const float*)d_in[22];
    float* out = (float*)d_out;

    // workspace layout (~141 MB total):
    // [0, 400128)               csr_ptr (N+1 ints)
    // [400128, 800256)          cursor
    // [800256, 7200256)         csr_src (E ints)
    // [7200256, 8117760)        wt: 8 bf16 tables [224][256] (hi/lo x 4 matrices)
    // [8117760, 20917760)       Xb (N x 64 bf16)
    // [20917760, 60917760)      h1b (N x 200 bf16)
    // [60917760, 140917760)     h2  (N x 200 fp32)
    char* ws = (char*)d_ws;
    int* csr_ptr = (int*)(ws + 0);
    int* cursor  = (int*)(ws + 400128);
    int* csr_src = (int*)(ws + 800256);
    short* wt    = (short*)(ws + 7200256);
    short* W1a2 = wt;                    // hi; lo at +WT_PER
    short* W1b2 = wt + 2 * WT_PER;
    short* W2a2 = wt + 4 * WT_PER;
    short* W2b2 = wt + 6 * WT_PER;
    short* Xb    = (short*)(ws + 8117760);
    __hip_bfloat16* h1b = (__hip_bfloat16*)(ws + 20917760);
    float* h2    = (float*)(ws + 60917760);
    int* bsums   = (int*)(ws + 20917760);  // alias h1b: dead until layer1 writes

    hipMemsetAsync(cursor, 0, N_NODES * sizeof(int), stream);
    hist_kernel<<<(N_EDGES + 255) / 256, 256, 0, stream>>>(ei, cursor);
    scan_part<<<NB_SCAN, 256, 0, stream>>>(cursor, bsums);
    scan_tops<<<1, 128, 0, stream>>>(bsums, csr_ptr);
    scan_fin<<<NB_SCAN, 256, 0, stream>>>(cursor, bsums, csr_ptr);
    fill_kernel<<<(N_EDGES + 255) / 256, 256, 0, stream>>>(ei, cursor, csr_src);
    prep_w<<<(4 * WT_PER + 255) / 256, 256, 0, stream>>>(W1a, W1b, W2a, W2b, wt);
    prep_x<<<(N_NODES * 64 + 255) / 256, 256, 0, stream>>>(x, Xb);

    const int NBLK = (N_NODES + 63) / 64;   // 1563
    gin_mfma<true><<<NBLK, 512, 0, stream>>>(Xb, csr_ptr, csr_src, eps1,
            W1a2, b1a, W1b2, b1b, bn1g, bn1b, bn1m, bn1v, h1b);
    gin_mfma<false><<<NBLK, 512, 0, stream>>>(h1b, csr_ptr, csr_src, eps2,
            W2a2, b2a, W2b2, b2b, bn2g, bn2b, bn2m, bn2v, h2);

    pool_fc_kernel<<<N_GRAPHS, 256, 0, stream>>>(h2, batch, Wfc, bfc, out);
}

// Round 10
// 850.595 us; speedup vs baseline: 1.2631x; 1.2631x over previous
//
#include <hip/hip_runtime.h>
#include <hip/hip_bf16.h>
#include <math.h>

#define N_NODES 100000
#define N_EDGES 1600000
#define F_IN 64
#define H_DIM 200
#define N_GRAPHS 512
#define NB_SCAN 98   // ceil(100000 / 1024)

#define WT_PER (224 * 224)   // one padded weight table (shorts)
#define SA 232               // LDS A-tile stride (shorts)

typedef __attribute__((ext_vector_type(8))) short short8v;   // 8 bf16 = 4 VGPR
typedef __attribute__((ext_vector_type(4))) float f32x4;     // mfma accumulator

// ---------------- CSR build: histogram by dst ----------------
__global__ void hist_kernel(const int* __restrict__ ei, int* __restrict__ cnt) {
    int i = blockIdx.x * blockDim.x + threadIdx.x;
    if (i < N_EDGES) atomicAdd(&cnt[ei[N_EDGES + i]], 1);
}

__global__ __launch_bounds__(256) void scan_part(const int* __restrict__ deg,
                                                 int* __restrict__ bsums) {
    int b = blockIdx.x, t = threadIdx.x;
    int i0 = b * 1024 + t * 4;
    int s = 0;
    #pragma unroll
    for (int k = 0; k < 4; ++k) { int i = i0 + k; if (i < N_NODES) s += deg[i]; }
    #pragma unroll
    for (int off = 32; off > 0; off >>= 1) s += __shfl_down(s, off, 64);
    __shared__ int wsum[4];
    if ((t & 63) == 0) wsum[t >> 6] = s;
    __syncthreads();
    if (t == 0) bsums[b] = wsum[0] + wsum[1] + wsum[2] + wsum[3];
}

__global__ void scan_tops(int* __restrict__ bsums, int* __restrict__ ptr) {
    __shared__ int sh[128];
    int t = threadIdx.x;
    int v = (t < NB_SCAN) ? bsums[t] : 0;
    sh[t] = v;
    __syncthreads();
    for (int off = 1; off < 128; off <<= 1) {
        int a = sh[t];
        int add = (t >= off) ? sh[t - off] : 0;
        __syncthreads();
        sh[t] = a + add;
        __syncthreads();
    }
    if (t < NB_SCAN) bsums[t] = sh[t] - v;
    if (t == 127) ptr[N_NODES] = sh[127];
}

__global__ __launch_bounds__(256) void scan_fin(int* __restrict__ deg_cursor,
                                                const int* __restrict__ bsums,
                                                int* __restrict__ ptr) {
    int b = blockIdx.x, t = threadIdx.x;
    int i0 = b * 1024 + t * 4;
    int d[4]; int s = 0;
    #pragma unroll
    for (int k = 0; k < 4; ++k) {
        int i = i0 + k;
        d[k] = (i < N_NODES) ? deg_cursor[i] : 0;
        s += d[k];
    }
    __shared__ int sh[256];
    sh[t] = s;
    __syncthreads();
    for (int off = 1; off < 256; off <<= 1) {
        int a = sh[t];
        int add = (t >= off) ? sh[t - off] : 0;
        __syncthreads();
        sh[t] = a + add;
        __syncthreads();
    }
    int run = bsums[b] + sh[t] - s;
    #pragma unroll
    for (int k = 0; k < 4; ++k) {
        int i = i0 + k;
        if (i < N_NODES) { ptr[i] = run; deg_cursor[i] = run; run += d[k]; }
    }
}

__global__ void fill_kernel(const int* __restrict__ ei, int* __restrict__ cursor,
                            int* __restrict__ csr_src) {
    int i = blockIdx.x * blockDim.x + threadIdx.x;
    if (i < N_EDGES) {
        int s = ei[i];
        int d = ei[N_EDGES + i];
        int p = atomicAdd(&cursor[d], 1);
        csr_src[p] = s;
    }
}

// helpers
__device__ __forceinline__ short f2bf(float f) {
    __hip_bfloat16 h = __float2bfloat16(f);
    return *reinterpret_cast<const short*>(&h);
}
__device__ __forceinline__ float bf2f(short s) {
    return __uint_as_float(((unsigned)(unsigned short)s) << 16);
}
__device__ __forceinline__ float4 bf4_to_f4(uint2 u) {
    float4 r;
    r.x = __uint_as_float(u.x << 16);
    r.y = __uint_as_float(u.x & 0xffff0000u);
    r.z = __uint_as_float(u.y << 16);
    r.w = __uint_as_float(u.y & 0xffff0000u);
    return r;
}

// ---------------- X fp32 -> bf16 ----------------
__global__ void prep_x(const float* __restrict__ X, short* __restrict__ Xb) {
    int i = blockIdx.x * 256 + threadIdx.x;
    if (i < N_NODES * 64) Xb[i] = f2bf(X[i]);
}

// ---------------- weight prep: W[K][200] fp32 -> hi/lo bf16 tables [224 cols][224 k] ----------------
__global__ void prep_w(const float* __restrict__ W1a, const float* __restrict__ W1b,
                       const float* __restrict__ W2a, const float* __restrict__ W2b,
                       short* __restrict__ wt) {
    int idx = blockIdx.x * 256 + threadIdx.x;
    if (idx >= 4 * WT_PER) return;
    int tsel = idx / WT_PER, rem = idx % WT_PER;
    int c = rem / 224, k = rem % 224;
    const float* W = (tsel == 0) ? W1a : (tsel == 1) ? W1b : (tsel == 2) ? W2a : W2b;
    int K = (tsel == 0) ? 64 : 200;
    float v = (k < K && c < 200) ? W[k * 200 + c] : 0.0f;   // pads MUST be zero
    short hi = f2bf(v);
    short lo = f2bf(v - bf2f(hi));
    wt[(2 * tsel) * WT_PER + rem] = hi;
    wt[(2 * tsel + 1) * WT_PER + rem] = lo;
}

// ---- gather batch helpers (8-deep / 4-deep) ----
__device__ __forceinline__ void gath8_l1(const short* __restrict__ Xb,
                                         const int* __restrict__ srcl,
                                         int j, int lane, float& a0, float& a1) {
    int s0 = srcl[j+0], s1 = srcl[j+1], s2 = srcl[j+2], s3 = srcl[j+3];
    int s4 = srcl[j+4], s5 = srcl[j+5], s6 = srcl[j+6], s7 = srcl[j+7];
    short f0 = Xb[(size_t)s0 * 64 + lane];
    short f1 = Xb[(size_t)s1 * 64 + lane];
    short f2 = Xb[(size_t)s2 * 64 + lane];
    short f3 = Xb[(size_t)s3 * 64 + lane];
    short f4 = Xb[(size_t)s4 * 64 + lane];
    short f5 = Xb[(size_t)s5 * 64 + lane];
    short f6 = Xb[(size_t)s6 * 64 + lane];
    short f7 = Xb[(size_t)s7 * 64 + lane];
    a0 += (bf2f(f0) + bf2f(f2)) + (bf2f(f4) + bf2f(f6));
    a1 += (bf2f(f1) + bf2f(f3)) + (bf2f(f5) + bf2f(f7));
}
__device__ __forceinline__ void gath4_l1(const short* __restrict__ Xb,
                                         const int* __restrict__ srcl,
                                         int j, int lane, float& a0, float& a1) {
    int s0 = srcl[j+0], s1 = srcl[j+1], s2 = srcl[j+2], s3 = srcl[j+3];
    a0 += bf2f(Xb[(size_t)s0 * 64 + lane]) + bf2f(Xb[(size_t)s2 * 64 + lane]);
    a1 += bf2f(Xb[(size_t)s1 * 64 + lane]) + bf2f(Xb[(size_t)s3 * 64 + lane]);
}
__device__ __forceinline__ void gath8_l2(const uint2* __restrict__ H2,
                                         const int* __restrict__ srcl,
                                         int j, int lane, float4& A0, float4& A1) {
    int s0 = srcl[j+0], s1 = srcl[j+1], s2 = srcl[j+2], s3 = srcl[j+3];
    int s4 = srcl[j+4], s5 = srcl[j+5], s6 = srcl[j+6], s7 = srcl[j+7];
    uint2 u0 = H2[(size_t)s0 * 50 + lane];
    uint2 u1 = H2[(size_t)s1 * 50 + lane];
    uint2 u2 = H2[(size_t)s2 * 50 + lane];
    uint2 u3 = H2[(size_t)s3 * 50 + lane];
    uint2 u4 = H2[(size_t)s4 * 50 + lane];
    uint2 u5 = H2[(size_t)s5 * 50 + lane];
    uint2 u6 = H2[(size_t)s6 * 50 + lane];
    uint2 u7 = H2[(size_t)s7 * 50 + lane];
    float4 f0 = bf4_to_f4(u0), f1 = bf4_to_f4(u1);
    float4 f2 = bf4_to_f4(u2), f3 = bf4_to_f4(u3);
    float4 f4 = bf4_to_f4(u4), f5 = bf4_to_f4(u5);
    float4 f6 = bf4_to_f4(u6), f7 = bf4_to_f4(u7);
    A0.x += (f0.x + f2.x) + (f4.x + f6.x);
    A0.y += (f0.y + f2.y) + (f4.y + f6.y);
    A0.z += (f0.z + f2.z) + (f4.z + f6.z);
    A0.w += (f0.w + f2.w) + (f4.w + f6.w);
    A1.x += (f1.x + f3.x) + (f5.x + f7.x);
    A1.y += (f1.y + f3.y) + (f5.y + f7.y);
    A1.z += (f1.z + f3.z) + (f5.z + f7.z);
    A1.w += (f1.w + f3.w) + (f5.w + f7.w);
}
__device__ __forceinline__ void gath4_l2(const uint2* __restrict__ H2,
                                         const int* __restrict__ srcl,
                                         int j, int lane, float4& A0, float4& A1) {
    int s0 = srcl[j+0], s1 = srcl[j+1], s2 = srcl[j+2], s3 = srcl[j+3];
    float4 f0 = bf4_to_f4(H2[(size_t)s0 * 50 + lane]);
    float4 f1 = bf4_to_f4(H2[(size_t)s1 * 50 + lane]);
    float4 f2 = bf4_to_f4(H2[(size_t)s2 * 50 + lane]);
    float4 f3 = bf4_to_f4(H2[(size_t)s3 * 50 + lane]);
    A0.x += f0.x + f2.x; A0.y += f0.y + f2.y;
    A0.z += f0.z + f2.z; A0.w += f0.w + f2.w;
    A1.x += f1.x + f3.x; A1.y += f1.y + f3.y;
    A1.z += f1.z + f3.z; A1.w += f1.w + f3.w;
}

// ---- split-bf16 MFMA tile GEMM ----
// A: row=l&15, k=8*(l>>4)+j ; B: col=l&15, same k ; acc: col=l&15, row=(l>>4)*4+i
// acc += Ah*Bh + Ah*Bl + Al*Bh  (Al*Bl dropped, ~2^-16 relative)
template <int NKS>
__device__ __forceinline__ void gemm_split(const short* __restrict__ SLh,
                                           const short* __restrict__ SLl,
                                           const short* __restrict__ Wh,
                                           const short* __restrict__ Wl,
                                           int l15, int lhi, int rt, int ch,
                                           f32x4 acc[7]) {
    const int arow = (rt * 16 + l15) * SA;
    for (int ks = 0; ks < NKS; ++ks) {
        const int k0 = ks * 32 + 8 * lhi;
        short8v ah = *reinterpret_cast<const short8v*>(SLh + arow + k0);
        short8v al = *reinterpret_cast<const short8v*>(SLl + arow + k0);
        #pragma unroll
        for (int ct = 0; ct < 7; ++ct) {
            const int wrow = (ch * 7 + ct) * 16 + l15;
            short8v bh = *reinterpret_cast<const short8v*>(Wh + wrow * 224 + k0);
            short8v bl = *reinterpret_cast<const short8v*>(Wl + wrow * 224 + k0);
            acc[ct] = __builtin_amdgcn_mfma_f32_16x16x32_bf16(ah, bh, acc[ct], 0, 0, 0);
            acc[ct] = __builtin_amdgcn_mfma_f32_16x16x32_bf16(ah, bl, acc[ct], 0, 0, 0);
            acc[ct] = __builtin_amdgcn_mfma_f32_16x16x32_bf16(al, bh, acc[ct], 0, 0, 0);
        }
    }
}

// ---------------- fused GIN layer: gather -> split-MFMA GEMM1 -> relu -> GEMM2 -> BN ----
// 512 threads = 8 waves; 64 nodes/block; LDS 59.4KB -> 2 blocks/CU; (512,4) = 128-reg cap
// (R5's proven spill-free regime). Gather: DUAL-ROW per wave, 8-deep each =
// 16 outstanding row-loads/wave -> 256/CU (2x R5's 128, the empirical throughput knob).
// GEMM: wave = (row-tile rt = wid>>1) x (col-half ch = wid&1, 7 tiles); ONE reused acc[7].
template <bool FIRST>
__global__ __launch_bounds__(512, 4) void gin_mfma(
        const void* __restrict__ Xv,                 // bf16 [N][64] or bf16 [N][200]
        const int* __restrict__ ptr, const int* __restrict__ srcl,
        const float* __restrict__ eps_p,
        const short* __restrict__ Wa2,               // hi table; lo at +WT_PER
        const float* __restrict__ ba,
        const short* __restrict__ Wb2, const float* __restrict__ bb,
        const float* __restrict__ gamma, const float* __restrict__ beta,
        const float* __restrict__ mean, const float* __restrict__ var,
        void* __restrict__ outv) {                   // bf16 [N][200] or fp32 [N][200]
    __shared__ __align__(16) short SLh[64 * SA];     // 29,696 B
    __shared__ __align__(16) short SLl[64 * SA];     // 29,696 B
    const int t = threadIdx.x;
    const int lane = t & 63;
    const int wid = t >> 6;
    const int node0 = blockIdx.x * 64;
    const float ep = 1.0f + eps_p[0];

    // ---- zero the k-pad cols [200,232) so garbage never reaches MFMA ----
    for (int i = t; i < 64 * 32; i += 512) {
        int row = i >> 5, c = 200 + (i & 31);
        SLh[row * SA + c] = 0;
        SLl[row * SA + c] = 0;
    }

    // ---- gather phase: dual-row, 8-deep ILP each ----
    if (FIRST) {
        const short* Xb = (const short*)Xv;          // bf16 [N][64]
        for (int rr = 0; rr < 8; rr += 2) {
            int rowA = wid * 8 + rr, rowB = rowA + 1;
            int nodeA = node0 + rowA, nodeB = node0 + rowB;
            if (nodeA >= N_NODES) break;
            bool vB = (nodeB < N_NODES);
            int bA = ptr[nodeA], eA = ptr[nodeA + 1];
            int bB = 0, eB = 0;
            float a0 = ep * bf2f(Xb[(size_t)nodeA * 64 + lane]), a1 = 0.f;
            float c0 = 0.f, c1 = 0.f;
            if (vB) {
                bB = ptr[nodeB]; eB = ptr[nodeB + 1];
                c0 = ep * bf2f(Xb[(size_t)nodeB * 64 + lane]);
            }
            int jA = bA, jB = bB;
            while (jA + 8 <= eA && jB + 8 <= eB) {   // 16 loads in flight
                gath8_l1(Xb, srcl, jA, lane, a0, a1);
                gath8_l1(Xb, srcl, jB, lane, c0, c1);
                jA += 8; jB += 8;
            }
            for (; jA + 8 <= eA; jA += 8) gath8_l1(Xb, srcl, jA, lane, a0, a1);
            if (jA + 4 <= eA) { gath4_l1(Xb, srcl, jA, lane, a0, a1); jA += 4; }
            for (; jA < eA; ++jA) a0 += bf2f(Xb[(size_t)srcl[jA] * 64 + lane]);
            for (; jB + 8 <= eB; jB += 8) gath8_l1(Xb, srcl, jB, lane, c0, c1);
            if (jB + 4 <= eB) { gath4_l1(Xb, srcl, jB, lane, c0, c1); jB += 4; }
            for (; jB < eB; ++jB) c0 += bf2f(Xb[(size_t)srcl[jB] * 64 + lane]);
            float sA = a0 + a1;
            short hiA = f2bf(sA);
            SLh[rowA * SA + lane] = hiA;             // k = lane < 64
            SLl[rowA * SA + lane] = f2bf(sA - bf2f(hiA));
            if (vB) {
                float sB = c0 + c1;
                short hiB = f2bf(sB);
                SLh[rowB * SA + lane] = hiB;
                SLl[rowB * SA + lane] = f2bf(sB - bf2f(hiB));
            }
        }
    } else {
        const uint2* H2 = (const uint2*)Xv;          // bf16 rows: 50 x uint2
        for (int rr = 0; rr < 8; rr += 2) {
            int rowA = wid * 8 + rr, rowB = rowA + 1;
            int nodeA = node0 + rowA, nodeB = node0 + rowB;
            if (nodeA >= N_NODES) break;
            bool vB = (nodeB < N_NODES);
            if (lane < 50) {
                int bA = ptr[nodeA], eA = ptr[nodeA + 1];
                int bB = 0, eB = 0;
                float4 fsA = bf4_to_f4(H2[(size_t)nodeA * 50 + lane]);
                float4 A0 = make_float4(ep * fsA.x, ep * fsA.y, ep * fsA.z, ep * fsA.w);
                float4 A1 = make_float4(0.f, 0.f, 0.f, 0.f);
                float4 B0 = make_float4(0.f, 0.f, 0.f, 0.f);
                float4 B1 = make_float4(0.f, 0.f, 0.f, 0.f);
                if (vB) {
                    bB = ptr[nodeB]; eB = ptr[nodeB + 1];
                    float4 fsB = bf4_to_f4(H2[(size_t)nodeB * 50 + lane]);
                    B0 = make_float4(ep * fsB.x, ep * fsB.y, ep * fsB.z, ep * fsB.w);
                }
                int jA = bA, jB = bB;
                while (jA + 8 <= eA && jB + 8 <= eB) {   // 16 row-loads in flight
                    gath8_l2(H2, srcl, jA, lane, A0, A1);
                    gath8_l2(H2, srcl, jB, lane, B0, B1);
                    jA += 8; jB += 8;
                }
                for (; jA + 8 <= eA; jA += 8) gath8_l2(H2, srcl, jA, lane, A0, A1);
                if (jA + 4 <= eA) { gath4_l2(H2, srcl, jA, lane, A0, A1); jA += 4; }
                for (; jA < eA; ++jA) {
                    float4 f0 = bf4_to_f4(H2[(size_t)srcl[jA] * 50 + lane]);
                    A0.x += f0.x; A0.y += f0.y; A0.z += f0.z; A0.w += f0.w;
                }
                for (; jB + 8 <= eB; jB += 8) gath8_l2(H2, srcl, jB, lane, B0, B1);
                if (jB + 4 <= eB) { gath4_l2(H2, srcl, jB, lane, B0, B1); jB += 4; }
                for (; jB < eB; ++jB) {
                    float4 f0 = bf4_to_f4(H2[(size_t)srcl[jB] * 50 + lane]);
                    B0.x += f0.x; B0.y += f0.y; B0.z += f0.z; B0.w += f0.w;
                }
                {
                    float sx = A0.x + A1.x, sy = A0.y + A1.y;
                    float sz = A0.z + A1.z, sw = A0.w + A1.w;
                    short4 ph, pl;
                    ph.x = f2bf(sx); pl.x = f2bf(sx - bf2f(ph.x));
                    ph.y = f2bf(sy); pl.y = f2bf(sy - bf2f(ph.y));
                    ph.z = f2bf(sz); pl.z = f2bf(sz - bf2f(ph.z));
                    ph.w = f2bf(sw); pl.w = f2bf(sw - bf2f(ph.w));
                    *reinterpret_cast<short4*>(&SLh[rowA * SA + 4 * lane]) = ph;
                    *reinterpret_cast<short4*>(&SLl[rowA * SA + 4 * lane]) = pl;
                }
                if (vB) {
                    float sx = B0.x + B1.x, sy = B0.y + B1.y;
                    float sz = B0.z + B1.z, sw = B0.w + B1.w;
                    short4 ph, pl;
                    ph.x = f2bf(sx); pl.x = f2bf(sx - bf2f(ph.x));
                    ph.y = f2bf(sy); pl.y = f2bf(sy - bf2f(ph.y));
                    ph.z = f2bf(sz); pl.z = f2bf(sz - bf2f(ph.z));
                    ph.w = f2bf(sw); pl.w = f2bf(sw - bf2f(ph.w));
                    *reinterpret_cast<short4*>(&SLh[rowB * SA + 4 * lane]) = ph;
                    *reinterpret_cast<short4*>(&SLl[rowB * SA + 4 * lane]) = pl;
                }
            }
        }
    }
    __syncthreads();

    const int l15 = lane & 15;
    const int lhi = lane >> 4;
    const int rt = wid >> 1;                         // row-tile 0..3
    const int ch = wid & 1;                          // column half

    // ---- single accumulator, reused by both GEMMs (28 AGPRs) ----
    f32x4 acc[7];

    // ---- GEMM1 ----
    #pragma unroll
    for (int i = 0; i < 7; ++i) acc[i] = (f32x4){0.f, 0.f, 0.f, 0.f};
    if (FIRST) gemm_split<2>(SLh, SLl, Wa2, Wa2 + WT_PER, l15, lhi, rt, ch, acc);
    else       gemm_split<7>(SLh, SLl, Wa2, Wa2 + WT_PER, l15, lhi, rt, ch, acc);
    __syncthreads();   // all A1 reads done before overwrite

    // ---- t = relu(acc + ba) -> SLh/SLl (cols < 200; pads still zero) ----
    #pragma unroll
    for (int i = 0; i < 7; ++i) {
        int col = (ch * 7 + i) * 16 + l15;
        if (col < 200) {
            float bv = ba[col];
            #pragma unroll
            for (int r = 0; r < 4; ++r) {
                int row = rt * 16 + lhi * 4 + r;
                float v = fmaxf(acc[i][r] + bv, 0.0f);
                short hi = f2bf(v);
                SLh[row * SA + col] = hi;
                SLl[row * SA + col] = f2bf(v - bf2f(hi));
            }
        }
    }
    __syncthreads();

    // ---- GEMM2 (K = 200 both layers), same acc re-zeroed ----
    #pragma unroll
    for (int i = 0; i < 7; ++i) acc[i] = (f32x4){0.f, 0.f, 0.f, 0.f};
    gemm_split<7>(SLh, SLl, Wb2, Wb2 + WT_PER, l15, lhi, rt, ch, acc);

    // ---- epilogue: relu + BN -> out ----
    #pragma unroll
    for (int i = 0; i < 7; ++i) {
        int col = (ch * 7 + i) * 16 + l15;
        if (col >= 200) continue;
        float bv = bb[col];
        float g0 = gamma[col], bt = beta[col], mn = mean[col];
        float inv = rsqrtf(var[col] + 1e-5f);
        #pragma unroll
        for (int r = 0; r < 4; ++r) {
            int row = rt * 16 + lhi * 4 + r;
            int node = node0 + row;
            if (node < N_NODES) {
                float v = fmaxf(acc[i][r] + bv, 0.0f);
                v = (v - mn) * inv * g0 + bt;
                if (FIRST) ((__hip_bfloat16*)outv)[(size_t)node * 200 + col] = __float2bfloat16(v);
                else       ((float*)outv)[(size_t)node * 200 + col] = v;
            }
        }
    }
}

// ---------------- fused pooling (sum+max) + FC + log_softmax ----------------
__device__ __forceinline__ int lower_bound_dev(const int* a, int n, int v) {
    int lo = 0, hi = n;
    while (lo < hi) { int mid = (lo + hi) >> 1; if (a[mid] < v) lo = mid + 1; else hi = mid; }
    return lo;
}

__global__ __launch_bounds__(256) void pool_fc_kernel(const float* __restrict__ h,
        const int* __restrict__ batch, const float* __restrict__ Wfc,
        const float* __restrict__ bfc, float* __restrict__ out) {
    int g = blockIdx.x;
    __shared__ int range[2];
    if (threadIdx.x == 0) range[0] = lower_bound_dev(batch, N_NODES, g);
    else if (threadIdx.x == 64) range[1] = lower_bound_dev(batch, N_NODES, g + 1);
    __syncthreads();
    int b = range[0], e = range[1];
    int d = threadIdx.x;
    float s0 = 0.f, s1 = 0.f, s2 = 0.f, s3 = 0.f, m = -3.0e38f;
    int n = b;
    if (d < 200) {
        for (; n + 4 <= e; n += 4) {   // 4 independent row-streams
            float v0 = h[(size_t)(n+0) * 200 + d];
            float v1 = h[(size_t)(n+1) * 200 + d];
            float v2 = h[(size_t)(n+2) * 200 + d];
            float v3 = h[(size_t)(n+3) * 200 + d];
            s0 += v0; s1 += v1; s2 += v2; s3 += v3;
            m = fmaxf(m, fmaxf(fmaxf(v0, v1), fmaxf(v2, v3)));
        }
        for (; n < e; ++n) {
            float v = h[(size_t)n * 200 + d];
            s0 += v;
            m = fmaxf(m, v);
        }
    }
    float s = (s0 + s1) + (s2 + s3);
    float c0 = 0.f, c1 = 0.f;
    if (d < 200) {
        c0 = s * Wfc[d * 2 + 0] + m * Wfc[(200 + d) * 2 + 0];
        c1 = s * Wfc[d * 2 + 1] + m * Wfc[(200 + d) * 2 + 1];
    }
    #pragma unroll
    for (int off = 32; off > 0; off >>= 1) {
        c0 += __shfl_down(c0, off, 64);
        c1 += __shfl_down(c1, off, 64);
    }
    __shared__ float r0[4], r1[4];
    int wid = threadIdx.x >> 6;
    if ((threadIdx.x & 63) == 0) { r0[wid] = c0; r1[wid] = c1; }
    __syncthreads();
    if (threadIdx.x == 0) {
        float l0 = r0[0] + r0[1] + r0[2] + r0[3] + bfc[0];
        float l1 = r1[0] + r1[1] + r1[2] + r1[3] + bfc[1];
        float mx = fmaxf(l0, l1);
        float lse = mx + logf(expf(l0 - mx) + expf(l1 - mx));
        out[g * 2 + 0] = l0 - lse;
        out[g * 2 + 1] = l1 - lse;
    }
}

// ---------------- launch ----------------
extern "C" void kernel_launch(void* const* d_in, const int* in_sizes, int n_in,
                              void* d_out, int out_size, void* d_ws, size_t ws_size,
                              hipStream_t stream) {
    const float* x    = (const float*)d_in[0];
    const int*   ei   = (const int*)d_in[1];
    const int*   batch= (const int*)d_in[2];
    const float* eps1 = (const float*)d_in[3];
    const float* W1a  = (const float*)d_in[4];
    const float* b1a  = (const float*)d_in[5];
    const float* W1b  = (const float*)d_in[6];
    const float* b1b  = (const float*)d_in[7];
    const float* bn1g = (const float*)d_in[8];
    const float* bn1b = (const float*)d_in[9];
    const float* bn1m = (const float*)d_in[10];
    const float* bn1v = (const float*)d_in[11];
    const float* eps2 = (const float*)d_in[12];
    const float* W2a  = (const float*)d_in[13];
    const float* b2a  = (const float*)d_in[14];
    const float* W2b  = (const float*)d_in[15];
    const float* b2b  = (const float*)d_in[16];
    const float* bn2g = (const float*)d_in[17];
    const float* bn2b = (const float*)d_in[18];
    const float* bn2m = (const float*)d_in[19];
    const float* bn2v = (const float*)d_in[20];
    const float* Wfc  = (const float*)d_in[21];
    const float* bfc  = (const float*)d_in[22];
    float* out = (float*)d_out;

    // workspace layout (~141 MB total):
    // [0, 400128)               csr_ptr (N+1 ints)
    // [400128, 800256)          cursor
    // [800256, 7200256)         csr_src (E ints)
    // [7200256, 8003072)        wt: 8 bf16 tables [224][224] (hi/lo x 4 matrices)
    // [8003072, 20803072)       Xb (N x 64 bf16)
    // [20803072, 60803072)      h1b (N x 200 bf16)
    // [60803072, 140803072)     h2  (N x 200 fp32)
    char* ws = (char*)d_ws;
    int* csr_ptr = (int*)(ws + 0);
    int* cursor  = (int*)(ws + 400128);
    int* csr_src = (int*)(ws + 800256);
    short* wt    = (short*)(ws + 7200256);
    short* W1a2 = wt;                    // hi; lo at +WT_PER
    short* W1b2 = wt + 2 * WT_PER;
    short* W2a2 = wt + 4 * WT_PER;
    short* W2b2 = wt + 6 * WT_PER;
    short* Xb    = (short*)(ws + 8003072);
    __hip_bfloat16* h1b = (__hip_bfloat16*)(ws + 20803072);
    float* h2    = (float*)(ws + 60803072);
    int* bsums   = (int*)(ws + 20803072);  // alias h1b: dead until layer1 writes

    hipMemsetAsync(cursor, 0, N_NODES * sizeof(int), stream);
    hist_kernel<<<(N_EDGES + 255) / 256, 256, 0, stream>>>(ei, cursor);
    scan_part<<<NB_SCAN, 256, 0, stream>>>(cursor, bsums);
    scan_tops<<<1, 128, 0, stream>>>(bsums, csr_ptr);
    scan_fin<<<NB_SCAN, 256, 0, stream>>>(cursor, bsums, csr_ptr);
    fill_kernel<<<(N_EDGES + 255) / 256, 256, 0, stream>>>(ei, cursor, csr_src);
    prep_w<<<(4 * WT_PER + 255) / 256, 256, 0, stream>>>(W1a, W1b, W2a, W2b, wt);
    prep_x<<<(N_NODES * 64 + 255) / 256, 256, 0, stream>>>(x, Xb);

    const int NBLK = (N_NODES + 63) / 64;   // 1563
    gin_mfma<true><<<NBLK, 512, 0, stream>>>(Xb, csr_ptr, csr_src, eps1,
            W1a2, b1a, W1b2, b1b, bn1g, bn1b, bn1m, bn1v, h1b);
    gin_mfma<false><<<NBLK, 512, 0, stream>>>(h1b, csr_ptr, csr_src, eps2,
            W2a2, b2a, W2b2, b2b, bn2g, bn2b, bn2m, bn2v, h2);

    pool_fc_kernel<<<N_GRAPHS, 256, 0, stream>>>(h2, batch, Wfc, bfc, out);
}